// Round 7
// baseline (401.286 us; speedup 1.0000x reference)
//
#include <hip/hip_runtime.h>
#include <hip/hip_bf16.h>
#include <type_traits>

typedef unsigned short u16;
typedef __attribute__((ext_vector_type(4))) float f32x4;
typedef __attribute__((ext_vector_type(8))) short short8;
typedef __attribute__((ext_vector_type(8))) __bf16 bf16x8;

#define BB 2
#define NN 2048
#define DDIM 1024
#define HH 8
#define QHH 16
#define DHH 64

__device__ __forceinline__ float b2f(u16 v) {
    return __builtin_bit_cast(float, ((unsigned)v) << 16);
}
__device__ __forceinline__ u16 f2b(float f) {
    unsigned u = __builtin_bit_cast(unsigned, f);
    u += 0x7FFFu + ((u >> 16) & 1u);   // RNE
    return (u16)(u >> 16);
}
__device__ __forceinline__ float fastrcp(float x) {
#if __has_builtin(__builtin_amdgcn_rcpf)
    return __builtin_amdgcn_rcpf(x);
#else
    return 1.0f / x;
#endif
}
__device__ __forceinline__ float fastexp2(float x) {
#if __has_builtin(__builtin_amdgcn_exp2f)
    return __builtin_amdgcn_exp2f(x);  // v_exp_f32; NB: __exp2f collides with glibc
#else
    return exp2f(x);
#endif
}
__device__ __forceinline__ f32x4 mfma16(short8 a, short8 b, f32x4 c) {
    return __builtin_amdgcn_mfma_f32_16x16x32_bf16(
        __builtin_bit_cast(bf16x8, a), __builtin_bit_cast(bf16x8, b), c, 0, 0, 0);
}
// async global->LDS, 16B/lane; dst = uniform base + lane*16 (m97 pattern)
__device__ __forceinline__ void stage16(const u16* g, u16* l, int lane) {
#if __has_builtin(__builtin_amdgcn_global_load_lds)
    __builtin_amdgcn_global_load_lds(
        (const __attribute__((address_space(1))) unsigned int*)g,
        (__attribute__((address_space(3))) unsigned int*)l, 16, 0, 0);
#else
    *(short8*)(l + lane * 8) = *(const short8*)g;
#endif
}

// ---------------- RMSNorm over tokens: [4096,1024] f32 -> bf16 ----------------
__global__ __launch_bounds__(256) void k_rmsnorm(const float* __restrict__ tokens,
                                                 const float* __restrict__ norm_w,
                                                 u16* __restrict__ xb) {
    const int row = blockIdx.x;
    const int tid = threadIdx.x;
    const float* xp = tokens + (size_t)row * DDIM + tid * 4;
    float4 raw = *(const float4*)xp;
    float ss = raw.x * raw.x + raw.y * raw.y + raw.z * raw.z + raw.w * raw.w;
#pragma unroll
    for (int d = 1; d < 64; d <<= 1) ss += __shfl_xor(ss, d);
    __shared__ float red[4];
    if ((tid & 63) == 0) red[tid >> 6] = ss;
    __syncthreads();
    float tot = red[0] + red[1] + red[2] + red[3];
    float r = rsqrtf(tot * (1.0f / 1024.0f) + 1.1920929e-7f);
    float4 wv = *(const float4*)(norm_w + tid * 4);
    ushort4 o;
    o.x = f2b(raw.x * r * wv.x);
    o.y = f2b(raw.y * r * wv.y);
    o.z = f2b(raw.z * r * wv.z);
    o.w = f2b(raw.w * r * wv.w);
    *(ushort4*)(xb + (size_t)row * DDIM + tid * 4) = o;
}

// ---------------- transpose f32 [R,C] -> bf16 [C,R] ----------------
__global__ __launch_bounds__(256) void k_transpose(const float* __restrict__ in,
                                                   u16* __restrict__ out, int R, int C) {
    __shared__ u16 tile[32][33];
    const int bc = blockIdx.x * 32, br = blockIdx.y * 32;
    const int tx = threadIdx.x & 31, ty = threadIdx.x >> 5;
#pragma unroll
    for (int i = 0; i < 32; i += 8) tile[ty + i][tx] = f2b(in[(size_t)(br + ty + i) * C + bc + tx]);
    __syncthreads();
#pragma unroll
    for (int i = 0; i < 32; i += 8) out[(size_t)(bc + ty + i) * R + br + tx] = tile[tx][ty + i];
}

// ---------------- GEMM: C[M,N] = A[M,K](bf16) x Bt[N,K](bf16), async LDS staging ----------------
template <typename OT>
__global__ __launch_bounds__(256) void k_gemm_bt(const u16* __restrict__ A,
                                                 const u16* __restrict__ Bt,
                                                 OT* __restrict__ C,
                                                 int M, int Ncols, int K) {
    __shared__ __attribute__((aligned(16))) u16 As[128 * 32];
    __shared__ __attribute__((aligned(16))) u16 Bs[128 * 32];
    const int tid = threadIdx.x;
    const int lane = tid & 63;
    const int w = tid >> 6;
    const int m0 = blockIdx.y * 128;
    const int n0 = blockIdx.x * 128;
    const int wr = (w >> 1) * 64;
    const int wc = (w & 1) * 64;
    const int lr = lane & 15;
    const int lq = lane >> 4;

    const int ch0 = w * 32;
    const u16* aSrc = A + (size_t)(m0 + ch0 + (lane >> 2)) * K + (lane & 3) * 8;
    const u16* bSrc = Bt + (size_t)(n0 + ch0 + (lane >> 2)) * K + (lane & 3) * 8;
    u16* aDst = As + ch0 * 32;
    u16* bDst = Bs + ch0 * 32;

    f32x4 acc[4][4];
#pragma unroll
    for (int i = 0; i < 4; i++)
#pragma unroll
        for (int j = 0; j < 4; j++) acc[i][j] = (f32x4){0.f, 0.f, 0.f, 0.f};

    for (int k0 = 0; k0 < K; k0 += 32) {
        __syncthreads();
        stage16(aSrc, aDst, lane);
        stage16(aSrc + (size_t)16 * K, aDst + 512, lane);
        stage16(bSrc, bDst, lane);
        stage16(bSrc + (size_t)16 * K, bDst + 512, lane);
        aSrc += 32;
        bSrc += 32;
        __syncthreads();
        short8 a[4], b[4];
#pragma unroll
        for (int mi = 0; mi < 4; ++mi) a[mi] = *(const short8*)&As[(wr + mi * 16 + lr) * 32 + lq * 8];
#pragma unroll
        for (int ni = 0; ni < 4; ++ni) b[ni] = *(const short8*)&Bs[(wc + ni * 16 + lr) * 32 + lq * 8];
#pragma unroll
        for (int mi = 0; mi < 4; ++mi)
#pragma unroll
            for (int ni = 0; ni < 4; ++ni) acc[mi][ni] = mfma16(a[mi], b[ni], acc[mi][ni]);
    }
#pragma unroll
    for (int mi = 0; mi < 4; ++mi)
#pragma unroll
        for (int ni = 0; ni < 4; ++ni)
#pragma unroll
            for (int r = 0; r < 4; ++r) {
                int row = m0 + wr + mi * 16 + lq * 4 + r;
                int col = n0 + wc + ni * 16 + lr;
                if constexpr (std::is_same_v<OT, u16>)
                    C[(size_t)row * Ncols + col] = f2b(acc[mi][ni][r]);
                else
                    C[(size_t)row * Ncols + col] = acc[mi][ni][r];
            }
}

// ---------------- per-head L2 norm + scale; emit qn [b,qh,n,dh], kn [b,h,n,dh], vt [b,h,dh,n] ----------------
__global__ __launch_bounds__(256) void k_headnorm(const u16* __restrict__ q_raw,
                                                  const u16* __restrict__ kv_raw,
                                                  const float* __restrict__ q_gamma,
                                                  const float* __restrict__ k_gamma,
                                                  u16* __restrict__ qn,
                                                  u16* __restrict__ kn,
                                                  u16* __restrict__ vt) {
    const int row = blockIdx.x;  // b*N + n
    const int b = row >> 11, n = row & 2047;
    const int lane = threadIdx.x & 63, w = threadIdx.x >> 6;
    const u16* qr = q_raw + (size_t)row * 1024;
    const u16* kvr = kv_raw + (size_t)row * 1024;
#pragma unroll
    for (int t = 0; t < 4; ++t) {
        int qh = w * 4 + t;
        float v = b2f(qr[qh * 64 + lane]);
        float ss = v * v;
#pragma unroll
        for (int d = 1; d < 64; d <<= 1) ss += __shfl_xor(ss, d);
        float nrm = fmaxf(sqrtf(ss), 1e-12f);
        float g = q_gamma[qh * 64 + lane];
        qn[((size_t)(b * QHH + qh) * NN + n) * 64 + lane] = f2b(v / nrm * (g + 1.0f) * 8.0f);
    }
#pragma unroll
    for (int t = 0; t < 2; ++t) {
        int kh = w * 2 + t;
        float v = b2f(kvr[kh * 64 + lane]);
        float ss = v * v;
#pragma unroll
        for (int d = 1; d < 64; d <<= 1) ss += __shfl_xor(ss, d);
        float nrm = fmaxf(sqrtf(ss), 1e-12f);
        float g = k_gamma[kh * 64 + lane];
        kn[((size_t)(b * HH + kh) * NN + n) * 64 + lane] = f2b(v / nrm * (g + 1.0f) * 8.0f);
        float vv = b2f(kvr[512 + kh * 64 + lane]);
        vt[((size_t)(b * HH + kh) * 64 + lane) * NN + n] = f2b(vv);
    }
}

// ---------------- flash attention v5: fixed-max softmax, poly-tanh softcap (1 trans/score),
// K double-buffered in registers (prefetch under softmax), LPT dispatch (heavy strips first) ----------------
__global__ __launch_bounds__(128) void k_attn(const u16* __restrict__ qn,
                                              const u16* __restrict__ kn,
                                              const u16* __restrict__ vt,
                                              u16* __restrict__ O) {
    const int bq = blockIdx.x;  // b*16+qh
    const int b = bq >> 4, qh = bq & 15;
    const int h = qh >> 1;
    const int lane = threadIdx.x & 63, w = threadIdx.x >> 6;  // w in {0,1}
    const int lr = lane & 15, lq = lane >> 4;
    // LPT: y is the slow grid dim -> ascending dispatch order; give heaviest strip the lowest y
    const int z = 63 - blockIdx.y;
    const int i0 = z * 32 + w * 16;

    const u16* Qp = qn + (size_t)(b * QHH + qh) * NN * 64;
    const u16* Kp = kn + (size_t)(b * HH + h) * NN * 64;
    const u16* Vp = vt + (size_t)(b * HH + h) * 64 * NN;
    u16* Op = O + (size_t)(b * QHH + qh) * NN * 64;

    constexpr int PST = 68;  // P row stride: breaks power-of-2 bank pattern (R3: conflicts -> 0)
    __shared__ __attribute__((aligned(16))) u16 Plds[2][16 * PST];
    u16* pl = Plds[w];
    u16* plw = pl + (lq * 4) * PST + lr;
    const u16* plr = pl + lr * PST + lq * 8;

    short8 qf0 = *(const short8*)&Qp[(size_t)(i0 + lr) * 64 + lq * 8];
    short8 qf1 = *(const short8*)&Qp[(size_t)(i0 + lr) * 64 + 32 + lq * 8];

    f32x4 of[4];
#pragma unroll
    for (int nt = 0; nt < 4; ++nt) of[nt] = (f32x4){0.f, 0.f, 0.f, 0.f};
    float lsum[4] = {0.f, 0.f, 0.f, 0.f};
    const int rowi_base = i0 + lq * 4;

    const u16* kq = Kp + (size_t)lr * 64 + lq * 8;  // + jt*4096 per tile, +ct*1024 intra
    const u16* vq = Vp + (size_t)lr * NN + lq * 8;  // + j0 per tile, +nt*16*NN intra

    const int ntile = (i0 >> 6) + 1;

    // K register double-buffer; preload tile 0
    short8 kf[2][8];
#pragma unroll
    for (int c2 = 0; c2 < 4; ++c2) {
        kf[0][2 * c2] = *(const short8*)&kq[c2 * 1024];
        kf[0][2 * c2 + 1] = *(const short8*)&kq[c2 * 1024 + 32];
    }

    for (int jt = 0; jt < ntile; ++jt) {
        const int cur = jt & 1, nxt = cur ^ 1;
        const bool masked = (jt == ntile - 1);
        const int j0 = jt << 6;
        // ---- S = Q K^T (16x64) from registers ----
        f32x4 s[4];
#pragma unroll
        for (int ct = 0; ct < 4; ++ct) {
            f32x4 t = (f32x4){0.f, 0.f, 0.f, 0.f};
            t = mfma16(qf0, kf[cur][2 * ct], t);
            t = mfma16(qf1, kf[cur][2 * ct + 1], t);
            s[ct] = t;
        }
        // ---- prefetch next tile's K (flies under softmax + DS + PV) ----
        if (jt + 1 < ntile) {
            const u16* kp1 = kq + (size_t)(jt + 1) * 4096;
#pragma unroll
            for (int c2 = 0; c2 < 4; ++c2) {
                kf[nxt][2 * c2] = *(const short8*)&kp1[c2 * 1024];
                kf[nxt][2 * c2 + 1] = *(const short8*)&kp1[c2 * 1024 + 32];
            }
        }
        // ---- V loads for this tile (awaited at PV) ----
        short8 vf0[4], vf1[4];
        const u16* vp = vq + j0;
#pragma unroll
        for (int nt = 0; nt < 4; ++nt) {
            vf0[nt] = *(const short8*)&vp[(size_t)nt * 16 * NN];
            vf1[nt] = *(const short8*)&vp[(size_t)nt * 16 * NN + 32];
        }
        // ---- softcap+softmax, fixed max 6.25: p = exp2(9.016844*(tanh(s/50)-1)),
        //      tanh via odd deg-9 poly on |x|<=~1.4 (err ~1e-4): ONE trans op per score ----
#pragma unroll
        for (int ct = 0; ct < 4; ++ct)
#pragma unroll
            for (int r = 0; r < 4; ++r) {
                float x = s[ct][r] * 0.02f;
                float y = x * x;
                float g = fmaf(y, fmaf(y, fmaf(y, fmaf(y, 0.0052188f, -0.0358520f),
                                               0.1236583f), -0.3312901f), 0.9999061f);
                float p = fastexp2(fmaf(x * g, 9.0168440f, -9.0168440f));
                if (masked) {
                    int col = j0 + ct * 16 + lr;
                    p = (col <= rowi_base + r) ? p : 0.0f;
                }
                lsum[r] += p;
                plw[r * PST + ct * 16] = f2b(p);
            }
        // C-layout -> LDS -> A-layout (wave-local; DS in-order per wave; pin compiler)
        asm volatile("s_waitcnt lgkmcnt(0)" ::: "memory");
        short8 pf0 = *(const short8*)&plr[0];
        short8 pf1 = *(const short8*)&plr[32];
#pragma unroll
        for (int nt = 0; nt < 4; ++nt) {
            of[nt] = mfma16(pf0, vf0[nt], of[nt]);
            of[nt] = mfma16(pf1, vf1[nt], of[nt]);
        }
    }
    // one row-sum reduction at the end
#pragma unroll
    for (int r = 0; r < 4; ++r) {
        float s2 = lsum[r];
#pragma unroll
        for (int d = 1; d < 16; d <<= 1) s2 += __shfl_xor(s2, d);
        lsum[r] = fastrcp(s2);
    }
#pragma unroll
    for (int nt = 0; nt < 4; ++nt)
#pragma unroll
        for (int r = 0; r < 4; ++r)
            Op[(size_t)(rowi_base + r) * 64 + nt * 16 + lr] = f2b(of[nt][r] * lsum[r]);
}

// ---------------- sum g=2 group outputs: AO[b,n,h*64+d] = O[b,2h,n,d]+O[b,2h+1,n,d] ----------------
__global__ __launch_bounds__(256) void k_gsum(const u16* __restrict__ O, u16* __restrict__ AO) {
    int idx = blockIdx.x * 256 + threadIdx.x;  // B*N*512
    int c = idx & 511, row = idx >> 9;
    int b = row >> 11, n = row & 2047;
    int hh = c >> 6, d = c & 63;
    float a = b2f(O[((size_t)(b * QHH + 2 * hh) * NN + n) * 64 + d]);
    float bb = b2f(O[((size_t)(b * QHH + 2 * hh + 1) * NN + n) * 64 + d]);
    AO[(size_t)row * 512 + c] = f2b(a + bb);
}

extern "C" void kernel_launch(void* const* d_in, const int* in_sizes, int n_in,
                              void* d_out, int out_size, void* d_ws, size_t ws_size,
                              hipStream_t stream) {
    const float* tokens = (const float*)d_in[0];
    const float* norm_w = (const float*)d_in[1];
    const float* Wq = (const float*)d_in[2];
    const float* Wkv = (const float*)d_in[3];
    const float* Wout = (const float*)d_in[4];
    const float* q_gamma = (const float*)d_in[5];
    const float* k_gamma = (const float*)d_in[6];
    float* out = (float*)d_out;

    char* ws = (char*)d_ws;
    u16* xb = (u16*)(ws + 0);             // 8 MB  [4096,1024]
    u16* WqT = (u16*)(ws + 8388608);      // 2 MB
    u16* WkvT = (u16*)(ws + 10485760);    // 2 MB
    u16* WoutT = (u16*)(ws + 12582912);   // 1 MB
    u16* q_raw = (u16*)(ws + 13631488);   // 8 MB
    u16* kv_raw = (u16*)(ws + 22020096);  // 8 MB
    u16* kn = (u16*)(ws + 30408704);      // 4 MB
    u16* vtb = (u16*)(ws + 34603008);     // 4 MB
    // total 38,797,312 B. Lifetime aliases (stream-ordered, no overlap):
    u16* qn = xb;       // xb dead after QKV GEMMs
    u16* Obuf = q_raw;  // q_raw dead after headnorm
    u16* AO = kv_raw;   // kv_raw dead after headnorm

    k_rmsnorm<<<4096, 256, 0, stream>>>(tokens, norm_w, xb);
    k_transpose<<<dim3(32, 32), 256, 0, stream>>>(Wq, WqT, 1024, 1024);
    k_transpose<<<dim3(32, 32), 256, 0, stream>>>(Wkv, WkvT, 1024, 1024);
    k_transpose<<<dim3(32, 16), 256, 0, stream>>>(Wout, WoutT, 512, 1024);
    k_gemm_bt<u16><<<dim3(8, 32), 256, 0, stream>>>(xb, WqT, q_raw, 4096, 1024, 1024);
    k_gemm_bt<u16><<<dim3(8, 32), 256, 0, stream>>>(xb, WkvT, kv_raw, 4096, 1024, 1024);
    k_headnorm<<<4096, 256, 0, stream>>>(q_raw, kv_raw, q_gamma, k_gamma, qn, kn, vtb);
    k_attn<<<dim3(32, 64), 128, 0, stream>>>(qn, kn, vtb, Obuf);
    k_gsum<<<8192, 256, 0, stream>>>(Obuf, AO);
    k_gemm_bt<float><<<dim3(8, 32), 256, 0, stream>>>(AO, WoutT, out, 4096, 1024, 512);
}

// Round 8
// 292.573 us; speedup vs baseline: 1.3716x; 1.3716x over previous
//
#include <hip/hip_runtime.h>
#include <hip/hip_bf16.h>
#include <type_traits>

typedef unsigned short u16;
typedef __attribute__((ext_vector_type(4))) float f32x4;
typedef __attribute__((ext_vector_type(8))) short short8;
typedef __attribute__((ext_vector_type(8))) __bf16 bf16x8;

#define BB 2
#define NN 2048
#define DDIM 1024
#define HH 8
#define QHH 16
#define DHH 64

__device__ __forceinline__ float b2f(u16 v) {
    return __builtin_bit_cast(float, ((unsigned)v) << 16);
}
__device__ __forceinline__ u16 f2b(float f) {
    unsigned u = __builtin_bit_cast(unsigned, f);
    u += 0x7FFFu + ((u >> 16) & 1u);   // RNE
    return (u16)(u >> 16);
}
__device__ __forceinline__ float fastrcp(float x) {
#if __has_builtin(__builtin_amdgcn_rcpf)
    return __builtin_amdgcn_rcpf(x);
#else
    return 1.0f / x;
#endif
}
__device__ __forceinline__ float fastexp2(float x) {
#if __has_builtin(__builtin_amdgcn_exp2f)
    return __builtin_amdgcn_exp2f(x);  // v_exp_f32; NB: __exp2f collides with glibc
#else
    return exp2f(x);
#endif
}
__device__ __forceinline__ f32x4 mfma16(short8 a, short8 b, f32x4 c) {
    return __builtin_amdgcn_mfma_f32_16x16x32_bf16(
        __builtin_bit_cast(bf16x8, a), __builtin_bit_cast(bf16x8, b), c, 0, 0, 0);
}
// async global->LDS, 16B/lane; dst = uniform base + lane*16 (m97 pattern)
__device__ __forceinline__ void stage16(const u16* g, u16* l, int lane) {
#if __has_builtin(__builtin_amdgcn_global_load_lds)
    __builtin_amdgcn_global_load_lds(
        (const __attribute__((address_space(1))) unsigned int*)g,
        (__attribute__((address_space(3))) unsigned int*)l, 16, 0, 0);
#else
    *(short8*)(l + lane * 8) = *(const short8*)g;
#endif
}

// ---------------- RMSNorm over tokens: [4096,1024] f32 -> bf16 ----------------
__global__ __launch_bounds__(256) void k_rmsnorm(const float* __restrict__ tokens,
                                                 const float* __restrict__ norm_w,
                                                 u16* __restrict__ xb) {
    const int row = blockIdx.x;
    const int tid = threadIdx.x;
    const float* xp = tokens + (size_t)row * DDIM + tid * 4;
    float4 raw = *(const float4*)xp;
    float ss = raw.x * raw.x + raw.y * raw.y + raw.z * raw.z + raw.w * raw.w;
#pragma unroll
    for (int d = 1; d < 64; d <<= 1) ss += __shfl_xor(ss, d);
    __shared__ float red[4];
    if ((tid & 63) == 0) red[tid >> 6] = ss;
    __syncthreads();
    float tot = red[0] + red[1] + red[2] + red[3];
    float r = rsqrtf(tot * (1.0f / 1024.0f) + 1.1920929e-7f);
    float4 wv = *(const float4*)(norm_w + tid * 4);
    ushort4 o;
    o.x = f2b(raw.x * r * wv.x);
    o.y = f2b(raw.y * r * wv.y);
    o.z = f2b(raw.z * r * wv.z);
    o.w = f2b(raw.w * r * wv.w);
    *(ushort4*)(xb + (size_t)row * DDIM + tid * 4) = o;
}

// ---------------- transpose f32 [R,C] -> bf16 [C,R] ----------------
__global__ __launch_bounds__(256) void k_transpose(const float* __restrict__ in,
                                                   u16* __restrict__ out, int R, int C) {
    __shared__ u16 tile[32][33];
    const int bc = blockIdx.x * 32, br = blockIdx.y * 32;
    const int tx = threadIdx.x & 31, ty = threadIdx.x >> 5;
#pragma unroll
    for (int i = 0; i < 32; i += 8) tile[ty + i][tx] = f2b(in[(size_t)(br + ty + i) * C + bc + tx]);
    __syncthreads();
#pragma unroll
    for (int i = 0; i < 32; i += 8) out[(size_t)(bc + ty + i) * R + br + tx] = tile[tx][ty + i];
}

// ---------------- GEMM: C[M,N] = A[M,K](bf16) x Bt[N,K](bf16), 64x128 tile,
// async LDS staging; 512 blocks for M=4096 -> 2 blocks/CU (was 1, barrier-exposed) ----------------
template <typename OT>
__global__ __launch_bounds__(256) void k_gemm_bt(const u16* __restrict__ A,
                                                 const u16* __restrict__ Bt,
                                                 OT* __restrict__ C,
                                                 int M, int Ncols, int K) {
    __shared__ __attribute__((aligned(16))) u16 As[64 * 32];    // 4 KB
    __shared__ __attribute__((aligned(16))) u16 Bs[128 * 32];   // 8 KB
    const int tid = threadIdx.x;
    const int lane = tid & 63;
    const int w = tid >> 6;
    const int m0 = blockIdx.y * 64;
    const int n0 = blockIdx.x * 128;
    const int lr = lane & 15;
    const int lq = lane >> 4;

    // staging: A rows w*16 + (lane>>2); B rows w*32 + (lane>>2) and +16
    const u16* aSrc = A + (size_t)(m0 + w * 16 + (lane >> 2)) * K + (lane & 3) * 8;
    const u16* bSrc = Bt + (size_t)(n0 + w * 32 + (lane >> 2)) * K + (lane & 3) * 8;
    u16* aDst = As + w * 16 * 32;   // wave-uniform
    u16* bDst = Bs + w * 32 * 32;

    f32x4 acc[8];
#pragma unroll
    for (int i = 0; i < 8; i++) acc[i] = (f32x4){0.f, 0.f, 0.f, 0.f};

    for (int k0 = 0; k0 < K; k0 += 32) {
        __syncthreads();
        stage16(aSrc, aDst, lane);
        stage16(bSrc, bDst, lane);
        stage16(bSrc + (size_t)16 * K, bDst + 512, lane);
        aSrc += 32;
        bSrc += 32;
        __syncthreads();
        short8 a = *(const short8*)&As[(w * 16 + lr) * 32 + lq * 8];
#pragma unroll
        for (int nt = 0; nt < 8; ++nt) {
            short8 b = *(const short8*)&Bs[(nt * 16 + lr) * 32 + lq * 8];
            acc[nt] = mfma16(a, b, acc[nt]);
        }
    }
#pragma unroll
    for (int nt = 0; nt < 8; ++nt)
#pragma unroll
        for (int r = 0; r < 4; ++r) {
            int row = m0 + w * 16 + lq * 4 + r;
            int col = n0 + nt * 16 + lr;
            if constexpr (std::is_same_v<OT, u16>)
                C[(size_t)row * Ncols + col] = f2b(acc[nt][r]);
            else
                C[(size_t)row * Ncols + col] = acc[nt][r];
        }
}

// ---------------- per-head L2 norm + scale; emit qn [b,qh,n,dh], kn [b,h,n,dh], vt [b,h,dh,n] ----------------
__global__ __launch_bounds__(256) void k_headnorm(const u16* __restrict__ q_raw,
                                                  const u16* __restrict__ kv_raw,
                                                  const float* __restrict__ q_gamma,
                                                  const float* __restrict__ k_gamma,
                                                  u16* __restrict__ qn,
                                                  u16* __restrict__ kn,
                                                  u16* __restrict__ vt) {
    const int row = blockIdx.x;  // b*N + n
    const int b = row >> 11, n = row & 2047;
    const int lane = threadIdx.x & 63, w = threadIdx.x >> 6;
    const u16* qr = q_raw + (size_t)row * 1024;
    const u16* kvr = kv_raw + (size_t)row * 1024;
#pragma unroll
    for (int t = 0; t < 4; ++t) {
        int qh = w * 4 + t;
        float v = b2f(qr[qh * 64 + lane]);
        float ss = v * v;
#pragma unroll
        for (int d = 1; d < 64; d <<= 1) ss += __shfl_xor(ss, d);
        float nrm = fmaxf(sqrtf(ss), 1e-12f);
        float g = q_gamma[qh * 64 + lane];
        qn[((size_t)(b * QHH + qh) * NN + n) * 64 + lane] = f2b(v / nrm * (g + 1.0f) * 8.0f);
    }
#pragma unroll
    for (int t = 0; t < 2; ++t) {
        int kh = w * 2 + t;
        float v = b2f(kvr[kh * 64 + lane]);
        float ss = v * v;
#pragma unroll
        for (int d = 1; d < 64; d <<= 1) ss += __shfl_xor(ss, d);
        float nrm = fmaxf(sqrtf(ss), 1e-12f);
        float g = k_gamma[kh * 64 + lane];
        kn[((size_t)(b * HH + kh) * NN + n) * 64 + lane] = f2b(v / nrm * (g + 1.0f) * 8.0f);
        float vv = b2f(kvr[512 + kh * 64 + lane]);
        vt[((size_t)(b * HH + kh) * 64 + lane) * NN + n] = f2b(vv);
    }
}

// ---------------- flash attention v6: fixed-max softmax, poly-tanh (1 trans/score),
// depth-2 software pipeline with NAMED double buffers (no dynamic indexing -> no scratch spill!),
// QK(jt+1) overlapped with P's DS round-trip; LPT dispatch (heavy strips first) ----------------
__global__ __launch_bounds__(128) void k_attn(const u16* __restrict__ qn,
                                              const u16* __restrict__ kn,
                                              const u16* __restrict__ vt,
                                              u16* __restrict__ O) {
    const int bq = blockIdx.x;  // b*16+qh
    const int b = bq >> 4, qh = bq & 15;
    const int h = qh >> 1;
    const int lane = threadIdx.x & 63, w = threadIdx.x >> 6;  // w in {0,1}
    const int lr = lane & 15, lq = lane >> 4;
    // LPT: y is the slow grid dim -> ascending dispatch; heaviest strip gets lowest y
    const int z = 63 - blockIdx.y;
    const int i0 = z * 32 + w * 16;

    const u16* Qp = qn + (size_t)(b * QHH + qh) * NN * 64;
    const u16* Kp = kn + (size_t)(b * HH + h) * NN * 64;
    const u16* Vp = vt + (size_t)(b * HH + h) * 64 * NN;
    u16* Op = O + (size_t)(b * QHH + qh) * NN * 64;

    constexpr int PST = 68;  // P row stride: breaks power-of-2 bank pattern (R3: conflicts -> 0)
    __shared__ __attribute__((aligned(16))) u16 Plds[2][16 * PST];
    u16* pl = Plds[w];
    u16* plw = pl + (lq * 4) * PST + lr;
    const u16* plr = pl + lr * PST + lq * 8;

    short8 qf0 = *(const short8*)&Qp[(size_t)(i0 + lr) * 64 + lq * 8];
    short8 qf1 = *(const short8*)&Qp[(size_t)(i0 + lr) * 64 + 32 + lq * 8];

    f32x4 of[4];
#pragma unroll
    for (int nt = 0; nt < 4; ++nt) of[nt] = (f32x4){0.f, 0.f, 0.f, 0.f};
    float lsum[4] = {0.f, 0.f, 0.f, 0.f};
    const int rowi_base = i0 + lq * 4;

    const u16* kq = Kp + (size_t)lr * 64 + lq * 8;  // + jt*4096 per tile, +ct*1024 intra
    const u16* vq = Vp + (size_t)lr * NN + lq * 8;  // + j0 per tile, +nt*16*NN intra
    const int ntile = (i0 >> 6) + 1;

    short8 kA[8], kB[8];         // named buffers: indices below are all compile-time
    short8 v0[4], v1[4];
    f32x4 sa[4], sb[4];

    auto loadK = [&](short8(&kf)[8], int jt) {
        const u16* kp = kq + (size_t)jt * 4096;
#pragma unroll
        for (int c2 = 0; c2 < 4; ++c2) {
            kf[2 * c2] = *(const short8*)&kp[c2 * 1024];
            kf[2 * c2 + 1] = *(const short8*)&kp[c2 * 1024 + 32];
        }
    };
    auto QK = [&](f32x4(&s)[4], short8(&kf)[8]) {
#pragma unroll
        for (int ct = 0; ct < 4; ++ct) {
            f32x4 t = (f32x4){0.f, 0.f, 0.f, 0.f};
            t = mfma16(qf0, kf[2 * ct], t);
            t = mfma16(qf1, kf[2 * ct + 1], t);
            s[ct] = t;
        }
    };
    auto loadV = [&](int jt) {
        const u16* vp = vq + (jt << 6);
#pragma unroll
        for (int nt = 0; nt < 4; ++nt) {
            v0[nt] = *(const short8*)&vp[(size_t)nt * 16 * NN];
            v1[nt] = *(const short8*)&vp[(size_t)nt * 16 * NN + 32];
        }
    };
    // p = exp(6.25*tanh(s/50)-6.25) = exp2(9.016844*(tanh(x)-1)), x=s/50;
    // tanh via odd deg-9 poly (|x|<=~1.4, err ~1e-4): ONE trans op per score
    auto softmax_store = [&](f32x4(&s)[4], int jt) {
        const bool masked = (jt == ntile - 1);
        const int j0 = jt << 6;
#pragma unroll
        for (int ct = 0; ct < 4; ++ct)
#pragma unroll
            for (int r = 0; r < 4; ++r) {
                float x = s[ct][r] * 0.02f;
                float y = x * x;
                float g = fmaf(y, fmaf(y, fmaf(y, fmaf(y, 0.0052188f, -0.0358520f),
                                               0.1236583f), -0.3312901f), 0.9999061f);
                float p = fastexp2(fmaf(x * g, 9.0168440f, -9.0168440f));
                if (masked) {
                    int col = j0 + ct * 16 + lr;
                    p = (col <= rowi_base + r) ? p : 0.0f;
                }
                lsum[r] += p;
                plw[r * PST + ct * 16] = f2b(p);
            }
    };
    auto PV = [&]() {
        // C-layout -> LDS -> A-layout (wave-local; DS in-order per wave; pin compiler)
        asm volatile("s_waitcnt lgkmcnt(0)" ::: "memory");
        short8 pf0 = *(const short8*)&plr[0];
        short8 pf1 = *(const short8*)&plr[32];
#pragma unroll
        for (int nt = 0; nt < 4; ++nt) {
            of[nt] = mfma16(pf0, v0[nt], of[nt]);
            of[nt] = mfma16(pf1, v1[nt], of[nt]);
        }
    };

    loadK(kA, 0);
    QK(sa, kA);
    int jt = 0;
    while (true) {
        // even phase: consume sa, prefetch into kB
        if (jt + 1 < ntile) loadK(kB, jt + 1);
        loadV(jt);
        softmax_store(sa, jt);
        if (jt + 1 < ntile) QK(sb, kB);   // overlaps P's DS round-trip
        PV();
        if (++jt >= ntile) break;
        // odd phase: consume sb, prefetch into kA
        if (jt + 1 < ntile) loadK(kA, jt + 1);
        loadV(jt);
        softmax_store(sb, jt);
        if (jt + 1 < ntile) QK(sa, kA);
        PV();
        if (++jt >= ntile) break;
    }
    // one row-sum reduction at the end
#pragma unroll
    for (int r = 0; r < 4; ++r) {
        float s2 = lsum[r];
#pragma unroll
        for (int d = 1; d < 16; d <<= 1) s2 += __shfl_xor(s2, d);
        lsum[r] = fastrcp(s2);
    }
#pragma unroll
    for (int nt = 0; nt < 4; ++nt)
#pragma unroll
        for (int r = 0; r < 4; ++r)
            Op[(size_t)(rowi_base + r) * 64 + nt * 16 + lr] = f2b(of[nt][r] * lsum[r]);
}

// ---------------- sum g=2 group outputs: AO[b,n,h*64+d] = O[b,2h,n,d]+O[b,2h+1,n,d] ----------------
__global__ __launch_bounds__(256) void k_gsum(const u16* __restrict__ O, u16* __restrict__ AO) {
    int idx = blockIdx.x * 256 + threadIdx.x;  // B*N*512
    int c = idx & 511, row = idx >> 9;
    int b = row >> 11, n = row & 2047;
    int hh = c >> 6, d = c & 63;
    float a = b2f(O[((size_t)(b * QHH + 2 * hh) * NN + n) * 64 + d]);
    float bb = b2f(O[((size_t)(b * QHH + 2 * hh + 1) * NN + n) * 64 + d]);
    AO[(size_t)row * 512 + c] = f2b(a + bb);
}

extern "C" void kernel_launch(void* const* d_in, const int* in_sizes, int n_in,
                              void* d_out, int out_size, void* d_ws, size_t ws_size,
                              hipStream_t stream) {
    const float* tokens = (const float*)d_in[0];
    const float* norm_w = (const float*)d_in[1];
    const float* Wq = (const float*)d_in[2];
    const float* Wkv = (const float*)d_in[3];
    const float* Wout = (const float*)d_in[4];
    const float* q_gamma = (const float*)d_in[5];
    const float* k_gamma = (const float*)d_in[6];
    float* out = (float*)d_out;

    char* ws = (char*)d_ws;
    u16* xb = (u16*)(ws + 0);             // 8 MB  [4096,1024]
    u16* WqT = (u16*)(ws + 8388608);      // 2 MB
    u16* WkvT = (u16*)(ws + 10485760);    // 2 MB
    u16* WoutT = (u16*)(ws + 12582912);   // 1 MB
    u16* q_raw = (u16*)(ws + 13631488);   // 8 MB
    u16* kv_raw = (u16*)(ws + 22020096);  // 8 MB
    u16* kn = (u16*)(ws + 30408704);      // 4 MB
    u16* vtb = (u16*)(ws + 34603008);     // 4 MB
    // total 38,797,312 B. Lifetime aliases (stream-ordered, no overlap):
    u16* qn = xb;       // xb dead after QKV GEMMs
    u16* Obuf = q_raw;  // q_raw dead after headnorm
    u16* AO = kv_raw;   // kv_raw dead after headnorm

    k_rmsnorm<<<4096, 256, 0, stream>>>(tokens, norm_w, xb);
    k_transpose<<<dim3(32, 32), 256, 0, stream>>>(Wq, WqT, 1024, 1024);
    k_transpose<<<dim3(32, 32), 256, 0, stream>>>(Wkv, WkvT, 1024, 1024);
    k_transpose<<<dim3(32, 16), 256, 0, stream>>>(Wout, WoutT, 512, 1024);
    k_gemm_bt<u16><<<dim3(8, 64), 256, 0, stream>>>(xb, WqT, q_raw, 4096, 1024, 1024);
    k_gemm_bt<u16><<<dim3(8, 64), 256, 0, stream>>>(xb, WkvT, kv_raw, 4096, 1024, 1024);
    k_headnorm<<<4096, 256, 0, stream>>>(q_raw, kv_raw, q_gamma, k_gamma, qn, kn, vtb);
    k_attn<<<dim3(32, 64), 128, 0, stream>>>(qn, kn, vtb, Obuf);
    k_gsum<<<8192, 256, 0, stream>>>(Obuf, AO);
    k_gemm_bt<float><<<dim3(8, 64), 256, 0, stream>>>(AO, WoutT, out, 4096, 1024, 512);
}